// Round 1
// baseline (1588.434 us; speedup 1.0000x reference)
//
#include <hip/hip_runtime.h>

#define NB 4096          // number of boxes
#define NWRD 64          // 64-bit words per bitmask row (NB/64)
#define LLOC 16384       // number of locations
#define IOU_THR 0.5f

typedef unsigned long long u64;

// ---------------- Part 2: pred boxes + centerness (elementwise) --------------
__global__ void pred_kernel(const float* __restrict__ loc,
                            const float* __restrict__ deltas,
                            const int* __restrict__ stride_p,
                            float* __restrict__ out) {
    int i = blockIdx.x * blockDim.x + threadIdx.x;
    if (i >= LLOC) return;
    float s = (float)stride_p[0];
    float2 p = ((const float2*)loc)[i];
    float4 d = ((const float4*)deltas)[i];
    float c0 = fmaxf(d.x, 0.f), c1 = fmaxf(d.y, 0.f);
    float c2 = fmaxf(d.z, 0.f), c3 = fmaxf(d.w, 0.f);
    float b0 = p.x - c0 * s;
    float b1 = p.y - c1 * s;
    float b2 = p.x + c2 * s;
    float b3 = p.y + c3 * s;
    float lr_min = fminf(d.x, d.z), tb_min = fminf(d.y, d.w);
    float lr_max = fmaxf(d.x, d.z), tb_max = fmaxf(d.y, d.w);
    float cent = sqrtf((lr_min * tb_min) / (lr_max * tb_max));
    if (d.x == -1.f && d.y == -1.f && d.z == -1.f && d.w == -1.f) cent = -1.f;
    float* o = out + (size_t)i * 5;
    o[0] = b0; o[1] = b1; o[2] = b2; o[3] = b3; o[4] = cent;
}

// ---------------- max over all box coordinates -------------------------------
__global__ void maxc_kernel(const float* __restrict__ boxes, float* __restrict__ maxc) {
    __shared__ float red[4];
    int t = threadIdx.x;  // 256 threads
    float m = -3.0e38f;
    for (int i = t; i < NB * 4; i += 256) m = fmaxf(m, boxes[i]);
    for (int o = 32; o > 0; o >>= 1) m = fmaxf(m, __shfl_down(m, o));
    if ((t & 63) == 0) red[t >> 6] = m;
    __syncthreads();
    if (t == 0) *maxc = fmaxf(fmaxf(red[0], red[1]), fmaxf(red[2], red[3]));
}

// ---------------- class-offset boxes + areas ---------------------------------
__global__ void prep_kernel(const float* __restrict__ boxes, const int* __restrict__ cls,
                            const float* __restrict__ maxc,
                            float* __restrict__ bnms, float* __restrict__ areas) {
    int i = blockIdx.x * 256 + threadIdx.x;
    if (i >= NB) return;
    float off = (float)cls[i] * (maxc[0] + 1.0f);
    float4 b = ((const float4*)boxes)[i];
    b.x += off; b.y += off; b.z += off; b.w += off;
    ((float4*)bnms)[i] = b;
    areas[i] = (b.z - b.x) * (b.w - b.y);
}

// ---------------- rank sort by score (desc, tie -> lower index) --------------
__global__ void rank_kernel(const float* __restrict__ scores, int* __restrict__ sidx) {
    __shared__ float s[NB];
    int t = threadIdx.x;  // 256
    for (int i = t; i < NB; i += 256) s[i] = scores[i];
    __syncthreads();
    int i = blockIdx.x * 256 + t;
    float my = s[i];
    int rank = 0;
#pragma unroll 4
    for (int j = 0; j < NB; ++j) {
        float sj = s[j];
        rank += (sj > my) || (sj == my && j < i);
    }
    sidx[rank] = i;
}

// ---------------- gather boxes/areas into sorted order -----------------------
__global__ void gather_kernel(const float* __restrict__ bnms, const float* __restrict__ areas,
                              const int* __restrict__ sidx,
                              float* __restrict__ sboxes, float* __restrict__ sareas) {
    int i = blockIdx.x * 256 + threadIdx.x;
    if (i >= NB) return;
    int j = sidx[i];
    ((float4*)sboxes)[i] = ((const float4*)bnms)[j];
    sareas[i] = areas[j];
}

// ---------------- pairwise IoU > thr bitmask (64x64 tiles) -------------------
__global__ void mask_kernel(const float* __restrict__ sboxes, const float* __restrict__ sareas,
                            u64* __restrict__ mask) {
    __shared__ float4 cb[64];
    __shared__ float ca[64];
    int t = threadIdx.x;            // 64 threads = one wave
    int c = blockIdx.x, r = blockIdx.y;
    cb[t] = ((const float4*)sboxes)[c * 64 + t];
    ca[t] = sareas[c * 64 + t];
    __syncthreads();
    float4 rb = ((const float4*)sboxes)[r * 64 + t];
    float ra = sareas[r * 64 + t];
    u64 w = 0;
#pragma unroll 8
    for (int j = 0; j < 64; ++j) {
        float4 b = cb[j];
        float xi = fminf(rb.z, b.z) - fmaxf(rb.x, b.x);
        float yi = fminf(rb.w, b.w) - fmaxf(rb.y, b.y);
        float inter = fmaxf(xi, 0.f) * fmaxf(yi, 0.f);
        float iou = inter / (ra + ca[j] - inter);
        w |= (u64)(iou > IOU_THR) << j;
    }
    mask[(u64)(r * 64 + t) * NWRD + c] = w;
}

// ---------------- serial greedy scan (1 wave) --------------------------------
__device__ inline u64 shfl_u64(u64 v, int lane) {
    int lo = __shfl((int)(unsigned)(v & 0xffffffffull), lane);
    int hi = __shfl((int)(unsigned)(v >> 32), lane);
    return ((u64)(unsigned)hi << 32) | (unsigned)lo;
}

__global__ void scan_kernel(const u64* __restrict__ mask, const int* __restrict__ sidx,
                            float* __restrict__ keep_out) {
    int lane = threadIdx.x;  // 64 threads, 1 wave
    u64 acc = 0;             // lane w holds removed-word w (boxes 64w..64w+63)
    for (int b = 0; b < 64; ++b) {
        u64 gw = shfl_u64(acc, b);
        bool removed = (gw >> lane) & 1ull;
        // diagonal tile row word (symmetric => also the column word)
        u64 colw = mask[(u64)(b * 64 + lane) * NWRD + b];
        u64 decided = 0, keptm = 0;
        while (true) {
            u64 remb = __ballot(removed);
            u64 avail = ~(decided | remb);
            if (avail == 0ull) break;
            int i = __builtin_ctzll(avail);
            decided |= 1ull << i;
            keptm |= 1ull << i;
            removed = removed || ((colw >> i) & 1ull);
        }
        bool kept = (keptm >> lane) & 1ull;
        keep_out[sidx[b * 64 + lane]] = kept ? 1.0f : 0.0f;
        // merge kept rows into global removed accumulator (parallel across lanes)
        u64 km = keptm;
        while (km) {
            int i = __builtin_ctzll(km);
            km &= km - 1;
            acc |= mask[(u64)(b * 64 + i) * NWRD + lane];
        }
    }
}

extern "C" void kernel_launch(void* const* d_in, const int* in_sizes, int n_in,
                              void* d_out, int out_size, void* d_ws, size_t ws_size,
                              hipStream_t stream) {
    const float* boxes   = (const float*)d_in[0];   // (4096,4)
    const float* scores  = (const float*)d_in[1];   // (4096,)
    const int*   cls     = (const int*)d_in[2];     // (4096,)
    const float* loc     = (const float*)d_in[3];   // (16384,2)
    const float* deltas  = (const float*)d_in[4];   // (16384,4)
    const int*   stride  = (const int*)d_in[5];     // scalar

    float* out = (float*)d_out;
    float* keep_out = out;          // 4096 floats (bool as 0/1)
    float* pred_out = out + NB;     // 16384*5 floats

    // workspace layout
    char* ws = (char*)d_ws;
    float* maxc   = (float*)ws;                      ws += 16;
    float* bnms   = (float*)ws;                      ws += NB * 4 * sizeof(float);
    float* areas  = (float*)ws;                      ws += NB * sizeof(float);
    int*   sidx   = (int*)ws;                        ws += NB * sizeof(int);
    float* sboxes = (float*)ws;                      ws += NB * 4 * sizeof(float);
    float* sareas = (float*)ws;                      ws += NB * sizeof(float);
    u64*   mask   = (u64*)ws;                        // NB * NWRD * 8 = 2 MiB

    pred_kernel<<<LLOC / 256, 256, 0, stream>>>(loc, deltas, stride, pred_out);
    maxc_kernel<<<1, 256, 0, stream>>>(boxes, maxc);
    prep_kernel<<<NB / 256, 256, 0, stream>>>(boxes, cls, maxc, bnms, areas);
    rank_kernel<<<NB / 256, 256, 0, stream>>>(scores, sidx);
    gather_kernel<<<NB / 256, 256, 0, stream>>>(bnms, areas, sidx, sboxes, sareas);
    mask_kernel<<<dim3(NWRD, NWRD), 64, 0, stream>>>(sboxes, sareas, mask);
    scan_kernel<<<1, 64, 0, stream>>>(mask, sidx, keep_out);
}